// Round 1
// baseline (286.400 us; speedup 1.0000x reference)
//
#include <hip/hip_runtime.h>
#include <stdint.h>

// Problem shape (fixed): B=1, H=32, S=8192, D=128, ACT=2048
#define NROWS 32          // B*H
#define SLEN  8192        // S
#define DDIM  128         // D (floats per row; 512 bytes)
#define MACT  2048        // max_activated

// ---------------------------------------------------------------------------
// Kernel 1: per-(b,h)-row stable compaction of activated indices.
// One block per row, 1024 threads, 8 mask elements per thread.
// Includes an in-kernel dtype probe for the mask buffer, since the harness's
// upload format for a bool array is not specified:
//   mode 0: 1-byte bool      mode 1: 4-byte (int32 or float32 0/1.0)
//   mode 2: 8-byte int64
// Probe reads the first (NROWS*SLEN)/4 u32 words — exactly the buffer size in
// the 1-byte case, a prefix otherwise, so always in bounds.
// ---------------------------------------------------------------------------
__global__ __launch_bounds__(1024) void compact_kernel(
    const void* __restrict__ mask, int* __restrict__ ws_count,
    int* __restrict__ ws_idx) {
  const int row = blockIdx.x;
  const int tid = threadIdx.x;

  __shared__ int flags;
  if (tid == 0) flags = 0;
  __syncthreads();
  {
    const uint32_t* w = (const uint32_t*)mask;
    const int NW = (NROWS * SLEN) / 4;  // 65536 words
    int f = 0;
    for (int j = tid; j < NW; j += 1024) {
      uint32_t x = w[j];
      if (x > 1u) f |= 1;                       // word not in {0,1}
      if (x != 0u && x != 0x3F800000u) f |= 2;  // word not in {0, 1.0f}
      if ((j & 1) && x != 0u) f |= 4;           // odd-index word nonzero
    }
    if (f) atomicOr(&flags, f);
  }
  __syncthreads();
  int mode;
  {
    const int f = flags;
    if (!(f & 1))      mode = (f & 4) ? 1 : 2;  // all {0,1}: i32 vs i64
    else if (!(f & 2)) mode = 1;                // float 0/1.0 -> nonzero test ok
    else               mode = 0;                // packed 1-byte bool
  }

  // Load 8 consecutive mask elements per thread (thread t -> elems t*8..t*8+7).
  int bits = 0;
  {
    const int e0 = tid * 8;
    if (mode == 0) {
      const uint8_t* p = (const uint8_t*)mask + (size_t)row * SLEN;
      #pragma unroll
      for (int e = 0; e < 8; ++e) bits |= (p[e0 + e] != 0) << e;
    } else if (mode == 1) {
      const uint32_t* p = (const uint32_t*)mask + (size_t)row * SLEN;
      #pragma unroll
      for (int e = 0; e < 8; ++e) bits |= (p[e0 + e] != 0) << e;
    } else {
      const uint32_t* p = (const uint32_t*)mask + (size_t)row * SLEN * 2;
      #pragma unroll
      for (int e = 0; e < 8; ++e)
        bits |= ((p[2 * (e0 + e)] | p[2 * (e0 + e) + 1]) != 0) << e;
    }
  }
  const int cnt = __popc(bits);

  // Block-wide scan: wave(64) inclusive scan + scan of 16 wave sums.
  __shared__ int wave_sums[16];
  const int lane = tid & 63;
  const int wid = tid >> 6;
  int inc = cnt;
  #pragma unroll
  for (int off = 1; off < 64; off <<= 1) {
    int n = __shfl_up(inc, off, 64);
    if (lane >= off) inc += n;
  }
  if (lane == 63) wave_sums[wid] = inc;
  __syncthreads();
  if (wid == 0 && lane < 16) {
    int s = wave_sums[lane];
    #pragma unroll
    for (int off = 1; off < 16; off <<= 1) {
      int n = __shfl_up(s, off, 64);
      if (lane >= off) s += n;
    }
    wave_sums[lane] = s;
  }
  __syncthreads();
  const int excl = inc - cnt + (wid ? wave_sums[wid - 1] : 0);
  const int total = wave_sums[15];

  int pos = excl;
  #pragma unroll
  for (int e = 0; e < 8; ++e) {
    if (bits & (1 << e)) {
      if (pos < MACT) ws_idx[row * MACT + pos] = tid * 8 + e;
      ++pos;
    }
  }
  if (tid == 0) ws_count[row] = total;
}

// ---------------------------------------------------------------------------
// Kernel 2: gather. One 64-lane wave per (row, slot); lanes 0-31 copy the K
// row, lanes 32-63 the V row, one float4 (16B) per lane -> 512B per row.
// ---------------------------------------------------------------------------
__global__ __launch_bounds__(256) void gather_kernel(
    const float* __restrict__ kin, const float* __restrict__ vin,
    const int* __restrict__ ws_count, const int* __restrict__ ws_idx,
    float* __restrict__ out) {
  const int gw = blockIdx.x * 4 + (threadIdx.x >> 6);  // row*MACT + slot
  const int lane = threadIdx.x & 63;
  const int half = lane >> 5;  // 0 = K, 1 = V
  const int l = lane & 31;     // float4 index within the 128-float row
  const int row = gw >> 11;    // / MACT
  const int slot = gw & (MACT - 1);

  float4* dst = (float4*)(out + (size_t)half * NROWS * MACT * DDIM +
                          (size_t)(row * MACT + slot) * DDIM) + l;
  if (slot < ws_count[row]) {
    const int sidx = ws_idx[row * MACT + slot];
    const float* srcb = half ? vin : kin;
    const float4* src =
        (const float4*)(srcb + ((size_t)row * SLEN + sidx) * DDIM) + l;
    *dst = *src;
  } else {
    *dst = make_float4(0.f, 0.f, 0.f, 0.f);
  }
}

extern "C" void kernel_launch(void* const* d_in, const int* in_sizes, int n_in,
                              void* d_out, int out_size, void* d_ws,
                              size_t ws_size, hipStream_t stream) {
  const float* kin = (const float*)d_in[0];
  const float* vin = (const float*)d_in[1];
  const void* mask = d_in[2];
  // d_in[3] (max_activated) is a compile-time constant here (MACT).

  int* ws_count = (int*)d_ws;          // 32 ints
  int* ws_idx = ws_count + NROWS;      // 32*2048 ints

  hipLaunchKernelGGL(compact_kernel, dim3(NROWS), dim3(1024), 0, stream, mask,
                     ws_count, ws_idx);
  hipLaunchKernelGGL(gather_kernel, dim3(NROWS * MACT / 4), dim3(256), 0,
                     stream, kin, vin, ws_count, ws_idx, (float*)d_out);
}

// Round 2
// 259.485 us; speedup vs baseline: 1.1037x; 1.1037x over previous
//
#include <hip/hip_runtime.h>
#include <stdint.h>

// Problem shape (fixed): B=1, H=32, S=8192, D=128, ACT=2048
#define NROWS 32
#define SLEN  8192
#define DDIM  128
#define MACT  2048
#define SPB   64                // output slots per block
#define CPR   (MACT / SPB)      // 32 chunks per row
#define NTHR  256

// One fused kernel. Block (row, chunk):
//   phase A: probe mask dtype (4KB prefix), load row mask (32 elems/thread),
//            block-wide stable prefix scan, scatter this chunk's 64 compacted
//            source indices into LDS.
//   phase B: gather 64 K-rows + 64 V-rows (512B each) as float4, coalesced.
// Redundant scan per chunk is ~8-32KB of L2-cached mask reads -- free vs the
// 128KB of HBM gather traffic per block.
__global__ __launch_bounds__(NTHR) void fused_gather(
    const float* __restrict__ kin, const float* __restrict__ vin,
    const void* __restrict__ mask, float* __restrict__ out) {
  const int row = blockIdx.x >> 5;         // / CPR
  const int chunk = blockIdx.x & (CPR - 1);
  const int tid = threadIdx.x;
  const int lane = tid & 63, wid = tid >> 6;

  __shared__ int flags_s;
  __shared__ int wave_sums[NTHR / 64];
  __shared__ int sidx[SPB];

  if (tid == 0) flags_s = 0;
  __syncthreads();

  // ---- dtype probe over first 4KB of mask (safe under all layouts) ----
  // mode 0: 1-byte bool; mode 1: 4-byte (int32 or f32 0/1.0); mode 2: int64
  {
    const uint32_t* w = (const uint32_t*)mask;
    int f = 0;
    #pragma unroll
    for (int j = 0; j < 4; ++j) {
      const int ix = j * NTHR + tid;
      uint32_t x = w[ix];
      if (x > 1u) f |= 1;                       // word not in {0,1}
      if (x != 0u && x != 0x3F800000u) f |= 2;  // word not in {0, 1.0f}
      if ((ix & 1) && x != 0u) f |= 4;          // odd-index word nonzero
    }
    #pragma unroll
    for (int off = 32; off; off >>= 1) f |= __shfl_xor(f, off, 64);
    if (lane == 0 && f) atomicOr(&flags_s, f);
  }
  __syncthreads();
  int mode;
  {
    const int f = flags_s;
    if (!(f & 1))      mode = (f & 4) ? 1 : 2;
    else if (!(f & 2)) mode = 1;
    else               mode = 0;
  }

  // ---- load this thread's 32 mask elements (elements [tid*32, tid*32+32)) --
  uint32_t bits = 0;
  const int e0 = tid * 32;
  if (mode == 0) {
    const uint32_t* p = (const uint32_t*)mask + ((size_t)row * SLEN + e0) / 4;
    #pragma unroll
    for (int wv = 0; wv < 8; ++wv) {
      uint32_t x = p[wv];
      #pragma unroll
      for (int b = 0; b < 4; ++b)
        bits |= (uint32_t)(((x >> (8 * b)) & 0xFFu) != 0) << (wv * 4 + b);
    }
  } else if (mode == 1) {
    const uint32_t* p = (const uint32_t*)mask + (size_t)row * SLEN + e0;
    #pragma unroll
    for (int e = 0; e < 32; ++e) bits |= (uint32_t)(p[e] != 0u) << e;
  } else {
    const uint32_t* p = (const uint32_t*)mask + 2 * ((size_t)row * SLEN + e0);
    #pragma unroll
    for (int e = 0; e < 32; ++e)
      bits |= (uint32_t)((p[2 * e] | p[2 * e + 1]) != 0u) << e;
  }
  const int cnt = __popc(bits);

  // ---- block-wide scan (4 waves) ----
  int inc = cnt;
  #pragma unroll
  for (int off = 1; off < 64; off <<= 1) {
    int n = __shfl_up(inc, off, 64);
    if (lane >= off) inc += n;
  }
  if (lane == 63) wave_sums[wid] = inc;
  __syncthreads();
  int wpre = 0, total = 0;
  #pragma unroll
  for (int ww = 0; ww < NTHR / 64; ++ww) {
    const int s = wave_sums[ww];
    if (ww < wid) wpre += s;
    total += s;
  }
  const int excl = inc - cnt + wpre;

  // ---- scatter this chunk's compacted indices into LDS ----
  const int base = chunk * SPB;
  if (excl < base + SPB && excl + cnt > base) {
    int pos = excl;
    #pragma unroll
    for (int e = 0; e < 32; ++e) {
      if (bits & (1u << e)) {
        const int rel = pos - base;
        if ((unsigned)rel < (unsigned)SPB) sidx[rel] = e0 + e;
        ++pos;
      }
    }
  }
  __syncthreads();

  // ---- gather: 64 slots x 32 float4 for K, then V ----
  const float4* kf = (const float4*)kin + (size_t)row * SLEN * (DDIM / 4);
  const float4* vf = (const float4*)vin + (size_t)row * SLEN * (DDIM / 4);
  float4* outk = (float4*)out + ((size_t)row * MACT + base) * (DDIM / 4);
  float4* outv = outk + (size_t)NROWS * MACT * (DDIM / 4);
  const float4 z = make_float4(0.f, 0.f, 0.f, 0.f);

  #pragma unroll
  for (int j = 0; j < 8; ++j) {
    const int g = j * NTHR + tid;        // 0 .. 2047
    const int slot = g >> 5, ch = g & 31;
    const bool valid = (base + slot) < total;
    const int si = valid ? sidx[slot] : 0;
    float4 v = valid ? kf[(size_t)si * (DDIM / 4) + ch] : z;
    outk[(size_t)slot * (DDIM / 4) + ch] = v;
  }
  #pragma unroll
  for (int j = 0; j < 8; ++j) {
    const int g = j * NTHR + tid;
    const int slot = g >> 5, ch = g & 31;
    const bool valid = (base + slot) < total;
    const int si = valid ? sidx[slot] : 0;
    float4 v = valid ? vf[(size_t)si * (DDIM / 4) + ch] : z;
    outv[(size_t)slot * (DDIM / 4) + ch] = v;
  }
}

extern "C" void kernel_launch(void* const* d_in, const int* in_sizes, int n_in,
                              void* d_out, int out_size, void* d_ws,
                              size_t ws_size, hipStream_t stream) {
  const float* kin = (const float*)d_in[0];
  const float* vin = (const float*)d_in[1];
  const void* mask = d_in[2];
  // d_in[3] (max_activated) is compile-time MACT.
  hipLaunchKernelGGL(fused_gather, dim3(NROWS * CPR), dim3(NTHR), 0, stream,
                     kin, vin, mask, (float*)d_out);
}